// Round 17
// baseline (532.772 us; speedup 1.0000x reference)
//
#include <hip/hip_runtime.h>
#include <hip/hip_bf16.h>

typedef unsigned short u16;
typedef unsigned int u32;
typedef __attribute__((ext_vector_type(8))) short bf16x8;
typedef __attribute__((ext_vector_type(4))) float f32x4;
typedef __attribute__((ext_vector_type(4))) u16 u16x4;
typedef __attribute__((ext_vector_type(4))) u32 u32x4;

#define DEV static __device__ __forceinline__

DEV u16 f2bf(float x) {
  unsigned u = __builtin_bit_cast(unsigned, x);
  u += 0x7fffu + ((u >> 16) & 1u);   // RNE (finite values)
  return (u16)(u >> 16);
}
DEV float bf2f(u16 u) { return __builtin_bit_cast(float, ((unsigned)u) << 16); }

DEV u32 cvtpk(float lo, float hi) {   // packed f32->bf16 (RNE), gfx950
  u32 r;
  asm("v_cvt_pk_bf16_f32 %0, %1, %2" : "=v"(r) : "v"(lo), "v"(hi));
  return r;
}

DEV void glds16(const u16* g, u16* l) {
  __builtin_amdgcn_global_load_lds(
      (const __attribute__((address_space(1))) void*)g,
      (__attribute__((address_space(3))) void*)l, 16, 0, 0);
}

// ---- fused prep: [0,2048) xcvt | [2048,6144) transpose_w | [6144,6656) maskpack
__global__ __launch_bounds__(256) void prep(
    const float* __restrict__ k, const float* __restrict__ v,
    const float* __restrict__ q,
    const float* __restrict__ w0, const float* __restrict__ w1,
    const float* __restrict__ w2, const float* __restrict__ w3,
    const int* __restrict__ mask,
    u16* __restrict__ Xb, u16* __restrict__ WT,
    unsigned long long* __restrict__ Mb) {
  __shared__ u16 tile[32][33];
  const int bid = (int)blockIdx.x;
  const int tid = threadIdx.x;
  if (bid < 2048) {
    const size_t i0 = (size_t)bid * 256 + tid;
    for (size_t t = i0; t < 6291456; t += 524288) {
      const size_t e = t * 4;
      const float* src = (e < 8388608) ? k + e
                       : (e < 16777216) ? v + (e - 8388608)
                       : q + (e - 16777216);
      const f32x4 x = *(const f32x4*)src;
      u16x4 o;
#pragma unroll
      for (int r = 0; r < 4; ++r) o[r] = f2bf(x[r]);
      *(u16x4*)&Xb[e] = o;
    }
  } else if (bid < 6144) {
    const int lb = bid - 2048;
    const int mat = lb >> 10;
    const int bx = lb & 1023;
    const float* in = (mat == 0) ? w0 : (mat == 1) ? w1 : (mat == 2) ? w2 : w3;
    u16* o = WT + (size_t)mat * 1048576;
    const int bk = (bx & 31) << 5;
    const int bn = (bx >> 5) << 5;
    const int tx = tid & 31, ty = tid >> 5;
#pragma unroll
    for (int i = 0; i < 32; i += 8)
      tile[ty + i][tx] = f2bf(in[(size_t)(bk + ty + i) * 1024 + bn + tx]);
    __syncthreads();
#pragma unroll
    for (int i = 0; i < 32; i += 8)
      o[(size_t)(bn + ty + i) * 1024 + bk + tx] = tile[tx][ty + i];
  } else {
    const int lb = bid - 6144;
    const int qt = lb & 63, b = lb >> 6;
    const int w = tid >> 6, l = tid & 63;
    const int ln = l & 15, lg = l >> 4;
    const int* Mp = mask + ((size_t)b << 20) + ((size_t)(qt << 4) << 10);
    unsigned long long m = 0ull;
#pragma unroll
    for (int t = 0; t < 16; ++t) {
      const int key = (w << 8) + (t << 4) + ln;
#pragma unroll
      for (int r = 0; r < 4; ++r) {
        const int row = (lg << 2) + r;
        if (Mp[((size_t)row << 10) + key] != 0) m |= 1ull << ((t << 2) + r);
      }
    }
    Mb[((((size_t)b << 6) + qt) << 8) + tid] = m;
  }
}

// ---- QKV GEMM: 128x128 tile, BK=64, swizzled glds staging, T1 XCD swizzle ----
__global__ __launch_bounds__(256) void gemm_qkv(
    const u16* __restrict__ Xb, const u16* __restrict__ WTall,
    const float* __restrict__ bK, const float* __restrict__ bV,
    const float* __restrict__ bQ,
    u16* __restrict__ Kup, u16* __restrict__ VupT, u16* __restrict__ Qup) {
  __shared__ u16 As[8192];   // [128][64]
  __shared__ u16 Bs[8192];
  const int mode = blockIdx.y;
  const u16* A = Xb + (size_t)mode * 8388608;
  const u16* Bw = WTall + (size_t)mode * 1048576;
  const float* bias = (mode == 0) ? bK : (mode == 1) ? bV : bQ;

  const int tid = threadIdx.x;
  const int w = tid >> 6, l = tid & 63;
  const int ln = l & 15, lg = l >> 4;
  const int wr = w >> 1, wc = w & 1;
  const int bid0 = (int)blockIdx.x;
  const int sw = ((bid0 & 7) << 6) | (bid0 >> 3);
  const int mb = (sw >> 3) << 7;
  const int nb = (sw & 7) << 7;

  f32x4 acc[4][4] = {};
  const int ar = (wr << 6) + ln;
  const int br = (wc << 6) + ln;
  const int x7 = ln & 7;

  for (int k0 = 0; k0 < 1024; k0 += 64) {
#pragma unroll
    for (int i = 0; i < 4; ++i) {
      const int off = (i << 11) + (tid << 3);
      const int row = off >> 6;
      const int sc = ((((off >> 3) & 7) ^ (row & 7)) << 3);
      glds16(A + (size_t)(mb + row) * 1024 + k0 + sc, As + off);
      glds16(Bw + (size_t)(nb + row) * 1024 + k0 + sc, Bs + off);
    }
    __syncthreads();
#pragma unroll
    for (int kk = 0; kk < 2; ++kk) {
      const int g = (kk << 2) + lg;
      const int rc = (g ^ x7) << 3;
      bf16x8 aa[4], bb[4];
#pragma unroll
      for (int mt = 0; mt < 4; ++mt) {
        aa[mt] = *(const bf16x8*)&As[(ar + (mt << 4)) * 64 + rc];
        bb[mt] = *(const bf16x8*)&Bs[(br + (mt << 4)) * 64 + rc];
      }
#pragma unroll
      for (int mt = 0; mt < 4; ++mt)
#pragma unroll
        for (int nt = 0; nt < 4; ++nt)
          acc[mt][nt] = __builtin_amdgcn_mfma_f32_16x16x32_bf16(aa[mt], bb[nt], acc[mt][nt], 0, 0, 0);
    }
    __syncthreads();
  }

  const float scale = (mode == 2) ? 0.125f : 1.0f;
#pragma unroll
  for (int mt = 0; mt < 4; ++mt) {
    const int m0 = mb + (wr << 6) + (mt << 4) + (lg << 2);
    const int bb_ = m0 >> 10, s0 = m0 & 1023;
#pragma unroll
    for (int nt = 0; nt < 4; ++nt) {
      const int n = nb + (wc << 6) + (nt << 4) + ln;
      const float bval = bias[n];
      const int h = n >> 6, dh = n & 63;
      const size_t bh = (size_t)(bb_ * 16 + h);
      if (mode == 1) {
        const int wv = dh >> 4, lnv = dh & 15;
        const int kk = s0 >> 5, lgv = (s0 >> 3) & 3, e0 = s0 & 7;
        u16x4 pk;
#pragma unroll
        for (int r = 0; r < 4; ++r) pk[r] = f2bf(acc[mt][nt][r] + bval);
        *(u16x4*)&VupT[(bh << 16) + (wv << 14) + (kk << 9) + (lgv << 7) +
                       (lnv << 3) + e0] = pk;
      } else if (mode == 0) {
        const int half = dh >> 5, lg2 = (dh >> 3) & 3, e = dh & 7;
        const int T = s0 >> 4;
        u16* base = Kup + (bh << 16) + (T << 10) + (half << 9) + (lg2 << 7) + e;
#pragma unroll
        for (int r = 0; r < 4; ++r)
          base[((s0 & 15) + r) << 3] = f2bf(acc[mt][nt][r] + bval);
      } else {
#pragma unroll
        for (int r = 0; r < 4; ++r)
          Qup[((bh << 10) + s0 + r) * 64 + dh] =
              f2bf((acc[mt][nt][r] + bval) * scale);
      }
    }
  }
}

// ---- out-proj (BK=64 swizzled, T1) + folded combine2 (blocks >= 512) ----
__global__ __launch_bounds__(256) void gemm_out(
    const u16* __restrict__ Ctx, const u16* __restrict__ WTall,
    const float* __restrict__ bO, const u16* __restrict__ Pp,
    float* __restrict__ Out) {
  __shared__ u16 As[8192];
  __shared__ u16 Bs[8192];
  const int bid = (int)blockIdx.x;
  const int tid = threadIdx.x;

  if (bid >= 512) {
    float* Am = Out + 8388608;
    const size_t i = ((size_t)(bid - 512) * 256 + tid) * 8;
    const u16x4* q0 = (const u16x4*)&Pp[i];
    const u16x4* q1 = (const u16x4*)&Pp[8388608 + i];
    const u16x4 a0 = q0[0], a1 = q0[1], b0 = q1[0], b1 = q1[1];
    f32x4 lo, hi;
#pragma unroll
    for (int r = 0; r < 4; ++r) {
      lo[r] = (bf2f(a0[r]) + bf2f(b0[r])) * 0.0625f;
      hi[r] = (bf2f(a1[r]) + bf2f(b1[r])) * 0.0625f;
    }
    *(f32x4*)&Am[i] = lo;
    *(f32x4*)&Am[i + 4] = hi;
    return;
  }

  const u16* Bw = WTall + 3145728;
  const int w = tid >> 6, l = tid & 63;
  const int ln = l & 15, lg = l >> 4;
  const int wr = w >> 1, wc = w & 1;
  const int sw = ((bid & 7) << 6) | (bid >> 3);
  const int mb = (sw >> 3) << 7;
  const int nb = (sw & 7) << 7;

  f32x4 acc[4][4] = {};
  const int ar = (wr << 6) + ln;
  const int br = (wc << 6) + ln;
  const int x7 = ln & 7;

  for (int k0 = 0; k0 < 1024; k0 += 64) {
#pragma unroll
    for (int i = 0; i < 4; ++i) {
      const int off = (i << 11) + (tid << 3);
      const int row = off >> 6;
      const int sc = ((((off >> 3) & 7) ^ (row & 7)) << 3);
      glds16(Ctx + (size_t)(mb + row) * 1024 + k0 + sc, As + off);
      glds16(Bw + (size_t)(nb + row) * 1024 + k0 + sc, Bs + off);
    }
    __syncthreads();
#pragma unroll
    for (int kk = 0; kk < 2; ++kk) {
      const int g = (kk << 2) + lg;
      const int rc = (g ^ x7) << 3;
      bf16x8 aa[4], bb[4];
#pragma unroll
      for (int mt = 0; mt < 4; ++mt) {
        aa[mt] = *(const bf16x8*)&As[(ar + (mt << 4)) * 64 + rc];
        bb[mt] = *(const bf16x8*)&Bs[(br + (mt << 4)) * 64 + rc];
      }
#pragma unroll
      for (int mt = 0; mt < 4; ++mt)
#pragma unroll
        for (int nt = 0; nt < 4; ++nt)
          acc[mt][nt] = __builtin_amdgcn_mfma_f32_16x16x32_bf16(aa[mt], bb[nt], acc[mt][nt], 0, 0, 0);
    }
    __syncthreads();
  }
#pragma unroll
  for (int mt = 0; mt < 4; ++mt) {
    const int m0 = mb + (wr << 6) + (mt << 4) + (lg << 2);
#pragma unroll
    for (int nt = 0; nt < 4; ++nt) {
      const int n = nb + (wc << 6) + (nt << 4) + ln;
      const float bval = bO[n];
#pragma unroll
      for (int r = 0; r < 4; ++r)
        Out[(size_t)(m0 + r) * 1024 + n] = acc[mt][nt][r] + bval;
    }
  }
}

// ---- attention: 512 blocks x 512 threads; 2 wave-groups of 4 waves ----
// Group g handles heads g*8..g*8+7 with its own P_lds half (round-16 body).
__global__ __launch_bounds__(512, 4) void attn_kernel(
    const u16* __restrict__ Qup, const u16* __restrict__ Kf,
    const u16* __restrict__ Vf, const unsigned long long* __restrict__ Mb,
    u16* __restrict__ Ctx, u16* __restrict__ Pp) {
  __shared__ u16 P_lds[2][16384];    // per-group 32KB, XOR-swizzled rows
  __shared__ float red_s[2][4][16];
  __shared__ float invs[2][16];

  const int tid = threadIdx.x;       // 0..511
  const int g = tid >> 8;            // wave-group 0/1
  const int tidl = tid & 255;
  const int w = tidl >> 6, l = tid & 63;
  const int ln = l & 15, lg = l >> 4;
  const int kg8 = lg << 3;
  char* Pb = (char*)P_lds + (g << 15);

  // XCD swizzle: XCD x owns batch b = x (K+V = 4 MB = one L2)
  const int bid = (int)blockIdx.x;
  const int b = bid & 7;
  const int qt = bid >> 3;           // 0..63
  const int qb = qt << 4;

  const unsigned long long mbits = Mb[((((size_t)b << 6) + qt) << 8) + tidl];

  u32x4 accp[8];

#pragma unroll 1
  for (int hh = 0; hh < 8; ++hh) {
    const int h = (g << 3) + hh;
    const size_t bh = (size_t)(b * 16 + h);
    const u16* Qp = Qup + ((bh << 10) + qb) * 64;
    const u16* Kb = Kf + (bh << 16);
    const u16* Vb = Vf + (bh << 16) + ((size_t)w << 14);

    const bf16x8 qa0 = *(const bf16x8*)&Qp[ln * 64 + kg8];
    const bf16x8 qa1 = *(const bf16x8*)&Qp[ln * 64 + 32 + kg8];

    bf16x8 ka[3], kb[3];
#pragma unroll
    for (int p = 0; p < 3; ++p) {
      const int To = ((w << 4) + p) << 10;
      ka[p] = *(const bf16x8*)&Kb[To + (l << 3)];
      kb[p] = *(const bf16x8*)&Kb[To + 512 + (l << 3)];
    }

    float rsum[4] = {0, 0, 0, 0};
#pragma unroll
    for (int t = 0; t < 16; ++t) {
      const int s = t % 3;
      const bf16x8 k0 = ka[s], k1 = kb[s];
      if (t + 3 < 16) {
        const int To = ((w << 4) + t + 3) << 10;
        ka[s] = *(const bf16x8*)&Kb[To + (l << 3)];
        kb[s] = *(const bf16x8*)&Kb[To + 512 + (l << 3)];
      }
      f32x4 c = {0, 0, 0, 0};
      c = __builtin_amdgcn_mfma_f32_16x16x32_bf16(qa0, k0, c, 0, 0, 0);
      c = __builtin_amdgcn_mfma_f32_16x16x32_bf16(qa1, k1, c, 0, 0, 0);
      const int key = (w << 8) + (t << 4) + ln;
      float p[4];
#pragma unroll
      for (int r = 0; r < 4; ++r) {
        p[r] = ((mbits >> ((t << 2) + r)) & 1ull) ? 0.0f : __expf(c[r] - 4.0f);
        rsum[r] += p[r];
      }
      const u32 pk01 = cvtpk(p[0], p[1]);
      const u32 pk23 = cvtpk(p[2], p[3]);
      const int r0 = lg << 2;
      *(u16*)(Pb + ((((r0 + 0) << 11) + (key << 1)) ^ (((r0 + 0) & 7) << 4))) = (u16)pk01;
      *(u16*)(Pb + ((((r0 + 1) << 11) + (key << 1)) ^ (((r0 + 1) & 7) << 4))) = (u16)(pk01 >> 16);
      *(u16*)(Pb + ((((r0 + 2) << 11) + (key << 1)) ^ (((r0 + 2) & 7) << 4))) = (u16)pk23;
      *(u16*)(Pb + ((((r0 + 3) << 11) + (key << 1)) ^ (((r0 + 3) & 7) << 4))) = (u16)(pk23 >> 16);
    }

    // V prologue issued EARLY: loads fly under the shuffle-reduce VALU work
    bf16x8 vr[4];
#pragma unroll
    for (int p = 0; p < 4; ++p)
      vr[p] = *(const bf16x8*)&Vb[(p << 9) + (l << 3)];

#pragma unroll
    for (int off = 1; off < 16; off <<= 1) {
#pragma unroll
      for (int r = 0; r < 4; ++r) rsum[r] += __shfl_xor(rsum[r], off);
    }
    if (ln == 0) {
#pragma unroll
      for (int r = 0; r < 4; ++r) red_s[g][w][(lg << 2) + r] = rsum[r];
    }

    __syncthreads();
    float inv[4];
#pragma unroll
    for (int r = 0; r < 4; ++r) {
      const int row = (lg << 2) + r;
      inv[r] = 1.0f / (red_s[g][0][row] + red_s[g][1][row] +
                       red_s[g][2][row] + red_s[g][3][row]);
    }
    if (ln == 0) {
#pragma unroll
      for (int r = 0; r < 4; ++r) invs[g][(lg << 2) + r] = inv[r];
    }

    f32x4 c0 = {0, 0, 0, 0}, c1 = {0, 0, 0, 0};
#pragma unroll
    for (int kk = 0; kk < 32; ++kk) {
      const int s = kk & 3;
      const bf16x8 vb = vr[s];
      if (kk + 4 < 32)
        vr[s] = *(const bf16x8*)&Vb[((kk + 4) << 9) + (l << 3)];
      const int a0 = ((ln << 11) + (((kk << 5) + kg8) << 1)) ^ ((ln & 7) << 4);
      const bf16x8 pa = *(const bf16x8*)(Pb + a0);
      if (kk & 1)
        c1 = __builtin_amdgcn_mfma_f32_16x16x32_bf16(pa, vb, c1, 0, 0, 0);
      else
        c0 = __builtin_amdgcn_mfma_f32_16x16x32_bf16(pa, vb, c0, 0, 0, 0);
    }
    {
      const u32 q01 = cvtpk((c0[0] + c1[0]) * inv[0], (c0[1] + c1[1]) * inv[1]);
      const u32 q23 = cvtpk((c0[2] + c1[2]) * inv[2], (c0[3] + c1[3]) * inv[3]);
      u16* Cp = &Ctx[(((size_t)b << 10) + qb + (lg << 2)) * 1024 + (h << 6) + (w << 4) + ln];
      Cp[0] = (u16)q01;
      Cp[1024] = (u16)(q01 >> 16);
      Cp[2048] = (u16)q23;
      Cp[3072] = (u16)(q23 >> 16);
    }

    {
      const int row = tidl >> 4;
      const float iv = invs[g][row];
#pragma unroll
      for (int i = 0; i < 8; ++i) {
        const int chunk = (tidl & 15) + (i << 4);
        const int bo_ = ((row << 11) + (chunk << 4)) ^ ((row & 7) << 4);
        const u32x4 pu = *(const u32x4*)(Pb + bo_);
        u32x4 o;
#pragma unroll
        for (int j = 0; j < 4; ++j) {
          const float plo = __builtin_bit_cast(float, pu[j] << 16) * iv;
          const float phi = __builtin_bit_cast(float, pu[j] & 0xFFFF0000u) * iv;
          if (hh == 0) {
            o[j] = cvtpk(plo, phi);
          } else {
            const u32 a = accp[i][j];
            const float alo = __builtin_bit_cast(float, a << 16);
            const float ahi = __builtin_bit_cast(float, a & 0xFFFF0000u);
            o[j] = cvtpk(alo + plo, ahi + phi);
          }
        }
        accp[i] = o;
      }
    }
    __syncthreads();
  }

  {
    const int row = tidl >> 4;
    u16* Pg = Pp + ((size_t)g << 23) + (((size_t)b << 10) + qb + row) * 1024;
#pragma unroll
    for (int i = 0; i < 8; ++i) {
      const int chunk = (tidl & 15) + (i << 4);
      *(u32x4*)&Pg[chunk << 3] = accp[i];
    }
  }
}

extern "C" void kernel_launch(void* const* d_in, const int* in_sizes, int n_in,
                              void* d_out, int out_size, void* d_ws, size_t ws_size,
                              hipStream_t stream) {
  const float* k_in = (const float*)d_in[0];
  const float* v_in = (const float*)d_in[1];
  const float* q_in = (const float*)d_in[2];
  const int* mask = (const int*)d_in[3];
  const float* Wk = (const float*)d_in[4];
  const float* bk = (const float*)d_in[5];
  const float* Wv = (const float*)d_in[6];
  const float* bv = (const float*)d_in[7];
  const float* Wq = (const float*)d_in[8];
  const float* bq = (const float*)d_in[9];
  const float* Wo = (const float*)d_in[10];
  const float* bo = (const float*)d_in[11];

  float* out = (float*)d_out;                       // [8,1024,1024] f32 + amean

  // ws layout (u16 units): WT 4M | Xb [4M,29.36M) | Mb @29360128 (1MB) |
  //  Pp 2x8M @37748736 | Kf | Vf | Qup | Ctx  -> 209.7 MB total (proven)
  u16* ws = (u16*)d_ws;
  u16* WT = ws;
  u16* Xb = ws + 4194304;
  unsigned long long* Mb = (unsigned long long*)(ws + 29360128);
  u16* Pp = ws + 37748736;
  u16* Kf   = ws + 71303168;
  u16* Vf   = ws + 79691776;
  u16* Qup  = ws + 88080384;
  u16* Ctx  = ws + 96468992;

  prep<<<6656, 256, 0, stream>>>(k_in, v_in, q_in, Wk, Wv, Wq, Wo, mask,
                                 Xb, WT, Mb);
  gemm_qkv<<<dim3(512, 3), dim3(256), 0, stream>>>(
      Xb, WT, bk, bv, bq, Kf, Vf, Qup);
  attn_kernel<<<dim3(512), dim3(512), 0, stream>>>(
      Qup, Kf, Vf, Mb, Ctx, Pp);
  gemm_out<<<4608, 256, 0, stream>>>(Ctx, WT, bo, Pp, out);
}

// Round 18
// 316.520 us; speedup vs baseline: 1.6832x; 1.6832x over previous
//
#include <hip/hip_runtime.h>
#include <hip/hip_bf16.h>

typedef unsigned short u16;
typedef unsigned int u32;
typedef __attribute__((ext_vector_type(8))) short bf16x8;
typedef __attribute__((ext_vector_type(4))) float f32x4;
typedef __attribute__((ext_vector_type(4))) u16 u16x4;
typedef __attribute__((ext_vector_type(4))) u32 u32x4;

#define DEV static __device__ __forceinline__

DEV u16 f2bf(float x) {
  unsigned u = __builtin_bit_cast(unsigned, x);
  u += 0x7fffu + ((u >> 16) & 1u);   // RNE (finite values)
  return (u16)(u >> 16);
}
DEV float bf2f(u16 u) { return __builtin_bit_cast(float, ((unsigned)u) << 16); }

DEV u32 cvtpk(float lo, float hi) {   // packed f32->bf16 (RNE), gfx950
  u32 r;
  asm("v_cvt_pk_bf16_f32 %0, %1, %2" : "=v"(r) : "v"(lo), "v"(hi));
  return r;
}

DEV void glds16(const u16* g, u16* l) {
  __builtin_amdgcn_global_load_lds(
      (const __attribute__((address_space(1))) void*)g,
      (__attribute__((address_space(3))) void*)l, 16, 0, 0);
}

// ---- fused prep: [0,2048) xcvt | [2048,6144) transpose_w | [6144,6656) maskpack
__global__ __launch_bounds__(256) void prep(
    const float* __restrict__ k, const float* __restrict__ v,
    const float* __restrict__ q,
    const float* __restrict__ w0, const float* __restrict__ w1,
    const float* __restrict__ w2, const float* __restrict__ w3,
    const int* __restrict__ mask,
    u16* __restrict__ Xb, u16* __restrict__ WT,
    unsigned long long* __restrict__ Mb) {
  __shared__ u16 tile[32][33];
  const int bid = (int)blockIdx.x;
  const int tid = threadIdx.x;
  if (bid < 2048) {
    const size_t i0 = (size_t)bid * 256 + tid;
    for (size_t t = i0; t < 6291456; t += 524288) {
      const size_t e = t * 4;
      const float* src = (e < 8388608) ? k + e
                       : (e < 16777216) ? v + (e - 8388608)
                       : q + (e - 16777216);
      const f32x4 x = *(const f32x4*)src;
      u16x4 o;
#pragma unroll
      for (int r = 0; r < 4; ++r) o[r] = f2bf(x[r]);
      *(u16x4*)&Xb[e] = o;
    }
  } else if (bid < 6144) {
    const int lb = bid - 2048;
    const int mat = lb >> 10;
    const int bx = lb & 1023;
    const float* in = (mat == 0) ? w0 : (mat == 1) ? w1 : (mat == 2) ? w2 : w3;
    u16* o = WT + (size_t)mat * 1048576;
    const int bk = (bx & 31) << 5;
    const int bn = (bx >> 5) << 5;
    const int tx = tid & 31, ty = tid >> 5;
#pragma unroll
    for (int i = 0; i < 32; i += 8)
      tile[ty + i][tx] = f2bf(in[(size_t)(bk + ty + i) * 1024 + bn + tx]);
    __syncthreads();
#pragma unroll
    for (int i = 0; i < 32; i += 8)
      o[(size_t)(bn + ty + i) * 1024 + bk + tx] = tile[tx][ty + i];
  } else {
    const int lb = bid - 6144;
    const int qt = lb & 63, b = lb >> 6;
    const int w = tid >> 6, l = tid & 63;
    const int ln = l & 15, lg = l >> 4;
    const int* Mp = mask + ((size_t)b << 20) + ((size_t)(qt << 4) << 10);
    unsigned long long m = 0ull;
#pragma unroll
    for (int t = 0; t < 16; ++t) {
      const int key = (w << 8) + (t << 4) + ln;
#pragma unroll
      for (int r = 0; r < 4; ++r) {
        const int row = (lg << 2) + r;
        if (Mp[((size_t)row << 10) + key] != 0) m |= 1ull << ((t << 2) + r);
      }
    }
    Mb[((((size_t)b << 6) + qt) << 8) + tid] = m;
  }
}

// ---- QKV GEMM: 128x128 tile, BK=64, swizzled glds staging, T1 XCD swizzle ----
__global__ __launch_bounds__(256) void gemm_qkv(
    const u16* __restrict__ Xb, const u16* __restrict__ WTall,
    const float* __restrict__ bK, const float* __restrict__ bV,
    const float* __restrict__ bQ,
    u16* __restrict__ Kup, u16* __restrict__ VupT, u16* __restrict__ Qup) {
  __shared__ u16 As[8192];   // [128][64]
  __shared__ u16 Bs[8192];
  const int mode = blockIdx.y;
  const u16* A = Xb + (size_t)mode * 8388608;
  const u16* Bw = WTall + (size_t)mode * 1048576;
  const float* bias = (mode == 0) ? bK : (mode == 1) ? bV : bQ;

  const int tid = threadIdx.x;
  const int w = tid >> 6, l = tid & 63;
  const int ln = l & 15, lg = l >> 4;
  const int wr = w >> 1, wc = w & 1;
  const int bid0 = (int)blockIdx.x;
  const int sw = ((bid0 & 7) << 6) | (bid0 >> 3);
  const int mb = (sw >> 3) << 7;
  const int nb = (sw & 7) << 7;

  f32x4 acc[4][4] = {};
  const int ar = (wr << 6) + ln;
  const int br = (wc << 6) + ln;
  const int x7 = ln & 7;

  for (int k0 = 0; k0 < 1024; k0 += 64) {
#pragma unroll
    for (int i = 0; i < 4; ++i) {
      const int off = (i << 11) + (tid << 3);
      const int row = off >> 6;
      const int sc = ((((off >> 3) & 7) ^ (row & 7)) << 3);
      glds16(A + (size_t)(mb + row) * 1024 + k0 + sc, As + off);
      glds16(Bw + (size_t)(nb + row) * 1024 + k0 + sc, Bs + off);
    }
    __syncthreads();
#pragma unroll
    for (int kk = 0; kk < 2; ++kk) {
      const int g = (kk << 2) + lg;
      const int rc = (g ^ x7) << 3;
      bf16x8 aa[4], bb[4];
#pragma unroll
      for (int mt = 0; mt < 4; ++mt) {
        aa[mt] = *(const bf16x8*)&As[(ar + (mt << 4)) * 64 + rc];
        bb[mt] = *(const bf16x8*)&Bs[(br + (mt << 4)) * 64 + rc];
      }
#pragma unroll
      for (int mt = 0; mt < 4; ++mt)
#pragma unroll
        for (int nt = 0; nt < 4; ++nt)
          acc[mt][nt] = __builtin_amdgcn_mfma_f32_16x16x32_bf16(aa[mt], bb[nt], acc[mt][nt], 0, 0, 0);
    }
    __syncthreads();
  }

  const float scale = (mode == 2) ? 0.125f : 1.0f;
#pragma unroll
  for (int mt = 0; mt < 4; ++mt) {
    const int m0 = mb + (wr << 6) + (mt << 4) + (lg << 2);
    const int bb_ = m0 >> 10, s0 = m0 & 1023;
#pragma unroll
    for (int nt = 0; nt < 4; ++nt) {
      const int n = nb + (wc << 6) + (nt << 4) + ln;
      const float bval = bias[n];
      const int h = n >> 6, dh = n & 63;
      const size_t bh = (size_t)(bb_ * 16 + h);
      if (mode == 1) {
        const int wv = dh >> 4, lnv = dh & 15;
        const int kk = s0 >> 5, lgv = (s0 >> 3) & 3, e0 = s0 & 7;
        u16x4 pk;
#pragma unroll
        for (int r = 0; r < 4; ++r) pk[r] = f2bf(acc[mt][nt][r] + bval);
        *(u16x4*)&VupT[(bh << 16) + (wv << 14) + (kk << 9) + (lgv << 7) +
                       (lnv << 3) + e0] = pk;
      } else if (mode == 0) {
        const int half = dh >> 5, lg2 = (dh >> 3) & 3, e = dh & 7;
        const int T = s0 >> 4;
        u16* base = Kup + (bh << 16) + (T << 10) + (half << 9) + (lg2 << 7) + e;
#pragma unroll
        for (int r = 0; r < 4; ++r)
          base[((s0 & 15) + r) << 3] = f2bf(acc[mt][nt][r] + bval);
      } else {
#pragma unroll
        for (int r = 0; r < 4; ++r)
          Qup[((bh << 10) + s0 + r) * 64 + dh] =
              f2bf((acc[mt][nt][r] + bval) * scale);
      }
    }
  }
}

// ---- out-proj (BK=64 swizzled, T1) + folded combine2 (blocks >= 512) ----
__global__ __launch_bounds__(256) void gemm_out(
    const u16* __restrict__ Ctx, const u16* __restrict__ WTall,
    const float* __restrict__ bO, const u16* __restrict__ Pp,
    float* __restrict__ Out) {
  __shared__ u16 As[8192];
  __shared__ u16 Bs[8192];
  const int bid = (int)blockIdx.x;
  const int tid = threadIdx.x;

  if (bid >= 512) {
    float* Am = Out + 8388608;
    const size_t i = ((size_t)(bid - 512) * 256 + tid) * 8;
    const u16x4* q0 = (const u16x4*)&Pp[i];
    const u16x4* q1 = (const u16x4*)&Pp[8388608 + i];
    const u16x4 a0 = q0[0], a1 = q0[1], b0 = q1[0], b1 = q1[1];
    f32x4 lo, hi;
#pragma unroll
    for (int r = 0; r < 4; ++r) {
      lo[r] = (bf2f(a0[r]) + bf2f(b0[r])) * 0.0625f;
      hi[r] = (bf2f(a1[r]) + bf2f(b1[r])) * 0.0625f;
    }
    *(f32x4*)&Am[i] = lo;
    *(f32x4*)&Am[i + 4] = hi;
    return;
  }

  const u16* Bw = WTall + 3145728;
  const int w = tid >> 6, l = tid & 63;
  const int ln = l & 15, lg = l >> 4;
  const int wr = w >> 1, wc = w & 1;
  const int sw = ((bid & 7) << 6) | (bid >> 3);
  const int mb = (sw >> 3) << 7;
  const int nb = (sw & 7) << 7;

  f32x4 acc[4][4] = {};
  const int ar = (wr << 6) + ln;
  const int br = (wc << 6) + ln;
  const int x7 = ln & 7;

  for (int k0 = 0; k0 < 1024; k0 += 64) {
#pragma unroll
    for (int i = 0; i < 4; ++i) {
      const int off = (i << 11) + (tid << 3);
      const int row = off >> 6;
      const int sc = ((((off >> 3) & 7) ^ (row & 7)) << 3);
      glds16(Ctx + (size_t)(mb + row) * 1024 + k0 + sc, As + off);
      glds16(Bw + (size_t)(nb + row) * 1024 + k0 + sc, Bs + off);
    }
    __syncthreads();
#pragma unroll
    for (int kk = 0; kk < 2; ++kk) {
      const int g = (kk << 2) + lg;
      const int rc = (g ^ x7) << 3;
      bf16x8 aa[4], bb[4];
#pragma unroll
      for (int mt = 0; mt < 4; ++mt) {
        aa[mt] = *(const bf16x8*)&As[(ar + (mt << 4)) * 64 + rc];
        bb[mt] = *(const bf16x8*)&Bs[(br + (mt << 4)) * 64 + rc];
      }
#pragma unroll
      for (int mt = 0; mt < 4; ++mt)
#pragma unroll
        for (int nt = 0; nt < 4; ++nt)
          acc[mt][nt] = __builtin_amdgcn_mfma_f32_16x16x32_bf16(aa[mt], bb[nt], acc[mt][nt], 0, 0, 0);
    }
    __syncthreads();
  }
#pragma unroll
  for (int mt = 0; mt < 4; ++mt) {
    const int m0 = mb + (wr << 6) + (mt << 4) + (lg << 2);
#pragma unroll
    for (int nt = 0; nt < 4; ++nt) {
      const int n = nb + (wc << 6) + (nt << 4) + ln;
      const float bval = bO[n];
#pragma unroll
      for (int r = 0; r < 4; ++r)
        Out[(size_t)(m0 + r) * 1024 + n] = acc[mt][nt][r] + bval;
    }
  }
}

// ---- attention: 512 blocks x 512 threads; 2 wave-groups of 4 waves ----
// launch_bounds(512,2): cap 256 unified regs -> no spill (round-17 fix).
__global__ __launch_bounds__(512, 2) void attn_kernel(
    const u16* __restrict__ Qup, const u16* __restrict__ Kf,
    const u16* __restrict__ Vf, const unsigned long long* __restrict__ Mb,
    u16* __restrict__ Ctx, u16* __restrict__ Pp) {
  __shared__ u16 P_lds[2][16384];    // per-group 32KB, XOR-swizzled rows
  __shared__ float red_s[2][4][16];
  __shared__ float invs[2][16];

  const int tid = threadIdx.x;       // 0..511
  const int g = tid >> 8;            // wave-group 0/1
  const int tidl = tid & 255;
  const int w = tidl >> 6, l = tid & 63;
  const int ln = l & 15, lg = l >> 4;
  const int kg8 = lg << 3;
  char* Pb = (char*)P_lds + (g << 15);

  // XCD swizzle: XCD x owns batch b = x (K+V = 4 MB = one L2)
  const int bid = (int)blockIdx.x;
  const int b = bid & 7;
  const int qt = bid >> 3;           // 0..63
  const int qb = qt << 4;

  const unsigned long long mbits = Mb[((((size_t)b << 6) + qt) << 8) + tidl];

  u32x4 accp[8];

#pragma unroll 1
  for (int hh = 0; hh < 8; ++hh) {
    const int h = (g << 3) + hh;
    const size_t bh = (size_t)(b * 16 + h);
    const u16* Qp = Qup + ((bh << 10) + qb) * 64;
    const u16* Kb = Kf + (bh << 16);
    const u16* Vb = Vf + (bh << 16) + ((size_t)w << 14);

    const bf16x8 qa0 = *(const bf16x8*)&Qp[ln * 64 + kg8];
    const bf16x8 qa1 = *(const bf16x8*)&Qp[ln * 64 + 32 + kg8];

    bf16x8 ka[3], kb[3];
#pragma unroll
    for (int p = 0; p < 3; ++p) {
      const int To = ((w << 4) + p) << 10;
      ka[p] = *(const bf16x8*)&Kb[To + (l << 3)];
      kb[p] = *(const bf16x8*)&Kb[To + 512 + (l << 3)];
    }

    float rsum[4] = {0, 0, 0, 0};
#pragma unroll
    for (int t = 0; t < 16; ++t) {
      const int s = t % 3;
      const bf16x8 k0 = ka[s], k1 = kb[s];
      if (t + 3 < 16) {
        const int To = ((w << 4) + t + 3) << 10;
        ka[s] = *(const bf16x8*)&Kb[To + (l << 3)];
        kb[s] = *(const bf16x8*)&Kb[To + 512 + (l << 3)];
      }
      f32x4 c = {0, 0, 0, 0};
      c = __builtin_amdgcn_mfma_f32_16x16x32_bf16(qa0, k0, c, 0, 0, 0);
      c = __builtin_amdgcn_mfma_f32_16x16x32_bf16(qa1, k1, c, 0, 0, 0);
      const int key = (w << 8) + (t << 4) + ln;
      float p[4];
#pragma unroll
      for (int r = 0; r < 4; ++r) {
        p[r] = ((mbits >> ((t << 2) + r)) & 1ull) ? 0.0f : __expf(c[r] - 4.0f);
        rsum[r] += p[r];
      }
      const u32 pk01 = cvtpk(p[0], p[1]);
      const u32 pk23 = cvtpk(p[2], p[3]);
      const int r0 = lg << 2;
      *(u16*)(Pb + ((((r0 + 0) << 11) + (key << 1)) ^ (((r0 + 0) & 7) << 4))) = (u16)pk01;
      *(u16*)(Pb + ((((r0 + 1) << 11) + (key << 1)) ^ (((r0 + 1) & 7) << 4))) = (u16)(pk01 >> 16);
      *(u16*)(Pb + ((((r0 + 2) << 11) + (key << 1)) ^ (((r0 + 2) & 7) << 4))) = (u16)pk23;
      *(u16*)(Pb + ((((r0 + 3) << 11) + (key << 1)) ^ (((r0 + 3) & 7) << 4))) = (u16)(pk23 >> 16);
    }

    // V prologue issued EARLY: loads fly under the shuffle-reduce VALU work
    bf16x8 vr[4];
#pragma unroll
    for (int p = 0; p < 4; ++p)
      vr[p] = *(const bf16x8*)&Vb[(p << 9) + (l << 3)];

#pragma unroll
    for (int off = 1; off < 16; off <<= 1) {
#pragma unroll
      for (int r = 0; r < 4; ++r) rsum[r] += __shfl_xor(rsum[r], off);
    }
    if (ln == 0) {
#pragma unroll
      for (int r = 0; r < 4; ++r) red_s[g][w][(lg << 2) + r] = rsum[r];
    }

    __syncthreads();
    float inv[4];
#pragma unroll
    for (int r = 0; r < 4; ++r) {
      const int row = (lg << 2) + r;
      inv[r] = 1.0f / (red_s[g][0][row] + red_s[g][1][row] +
                       red_s[g][2][row] + red_s[g][3][row]);
    }
    if (ln == 0) {
#pragma unroll
      for (int r = 0; r < 4; ++r) invs[g][(lg << 2) + r] = inv[r];
    }

    f32x4 c0 = {0, 0, 0, 0}, c1 = {0, 0, 0, 0};
#pragma unroll
    for (int kk = 0; kk < 32; ++kk) {
      const int s = kk & 3;
      const bf16x8 vb = vr[s];
      if (kk + 4 < 32)
        vr[s] = *(const bf16x8*)&Vb[((kk + 4) << 9) + (l << 3)];
      const int a0 = ((ln << 11) + (((kk << 5) + kg8) << 1)) ^ ((ln & 7) << 4);
      const bf16x8 pa = *(const bf16x8*)(Pb + a0);
      if (kk & 1)
        c1 = __builtin_amdgcn_mfma_f32_16x16x32_bf16(pa, vb, c1, 0, 0, 0);
      else
        c0 = __builtin_amdgcn_mfma_f32_16x16x32_bf16(pa, vb, c0, 0, 0, 0);
    }
    {
      const u32 q01 = cvtpk((c0[0] + c1[0]) * inv[0], (c0[1] + c1[1]) * inv[1]);
      const u32 q23 = cvtpk((c0[2] + c1[2]) * inv[2], (c0[3] + c1[3]) * inv[3]);
      u16* Cp = &Ctx[(((size_t)b << 10) + qb + (lg << 2)) * 1024 + (h << 6) + (w << 4) + ln];
      Cp[0] = (u16)q01;
      Cp[1024] = (u16)(q01 >> 16);
      Cp[2048] = (u16)q23;
      Cp[3072] = (u16)(q23 >> 16);
    }

    {
      const int row = tidl >> 4;
      const float iv = invs[g][row];
#pragma unroll
      for (int i = 0; i < 8; ++i) {
        const int chunk = (tidl & 15) + (i << 4);
        const int bo_ = ((row << 11) + (chunk << 4)) ^ ((row & 7) << 4);
        const u32x4 pu = *(const u32x4*)(Pb + bo_);
        u32x4 o;
#pragma unroll
        for (int j = 0; j < 4; ++j) {
          const float plo = __builtin_bit_cast(float, pu[j] << 16) * iv;
          const float phi = __builtin_bit_cast(float, pu[j] & 0xFFFF0000u) * iv;
          if (hh == 0) {
            o[j] = cvtpk(plo, phi);
          } else {
            const u32 a = accp[i][j];
            const float alo = __builtin_bit_cast(float, a << 16);
            const float ahi = __builtin_bit_cast(float, a & 0xFFFF0000u);
            o[j] = cvtpk(alo + plo, ahi + phi);
          }
        }
        accp[i] = o;
      }
    }
    __syncthreads();
  }

  {
    const int row = tidl >> 4;
    u16* Pg = Pp + ((size_t)g << 23) + (((size_t)b << 10) + qb + row) * 1024;
#pragma unroll
    for (int i = 0; i < 8; ++i) {
      const int chunk = (tidl & 15) + (i << 4);
      *(u32x4*)&Pg[chunk << 3] = accp[i];
    }
  }
}

extern "C" void kernel_launch(void* const* d_in, const int* in_sizes, int n_in,
                              void* d_out, int out_size, void* d_ws, size_t ws_size,
                              hipStream_t stream) {
  const float* k_in = (const float*)d_in[0];
  const float* v_in = (const float*)d_in[1];
  const float* q_in = (const float*)d_in[2];
  const int* mask = (const int*)d_in[3];
  const float* Wk = (const float*)d_in[4];
  const float* bk = (const float*)d_in[5];
  const float* Wv = (const float*)d_in[6];
  const float* bv = (const float*)d_in[7];
  const float* Wq = (const float*)d_in[8];
  const float* bq = (const float*)d_in[9];
  const float* Wo = (const float*)d_in[10];
  const float* bo = (const float*)d_in[11];

  float* out = (float*)d_out;                       // [8,1024,1024] f32 + amean

  // ws layout (u16 units): WT 4M | Xb [4M,29.36M) | Mb @29360128 (1MB) |
  //  Pp 2x8M @37748736 | Kf | Vf | Qup | Ctx  -> 209.7 MB total (proven)
  u16* ws = (u16*)d_ws;
  u16* WT = ws;
  u16* Xb = ws + 4194304;
  unsigned long long* Mb = (unsigned long long*)(ws + 29360128);
  u16* Pp = ws + 37748736;
  u16* Kf   = ws + 71303168;
  u16* Vf   = ws + 79691776;
  u16* Qup  = ws + 88080384;
  u16* Ctx  = ws + 96468992;

  prep<<<6656, 256, 0, stream>>>(k_in, v_in, q_in, Wk, Wv, Wq, Wo, mask,
                                 Xb, WT, Mb);
  gemm_qkv<<<dim3(512, 3), dim3(256), 0, stream>>>(
      Xb, WT, bk, bv, bq, Kf, Vf, Qup);
  attn_kernel<<<dim3(512), dim3(512), 0, stream>>>(
      Qup, Kf, Vf, Mb, Ctx, Pp);
  gemm_out<<<4608, 256, 0, stream>>>(Ctx, WT, bo, Pp, out);
}

// Round 19
// 291.554 us; speedup vs baseline: 1.8274x; 1.0856x over previous
//
#include <hip/hip_runtime.h>
#include <hip/hip_bf16.h>

typedef unsigned short u16;
typedef unsigned int u32;
typedef __attribute__((ext_vector_type(8))) short bf16x8;
typedef __attribute__((ext_vector_type(4))) float f32x4;
typedef __attribute__((ext_vector_type(4))) u16 u16x4;
typedef __attribute__((ext_vector_type(4))) u32 u32x4;

#define DEV static __device__ __forceinline__

DEV u16 f2bf(float x) {
  unsigned u = __builtin_bit_cast(unsigned, x);
  u += 0x7fffu + ((u >> 16) & 1u);   // RNE (finite values)
  return (u16)(u >> 16);
}
DEV float bf2f(u16 u) { return __builtin_bit_cast(float, ((unsigned)u) << 16); }

DEV u32 cvtpk(float lo, float hi) {   // packed f32->bf16 (RNE), gfx950
  u32 r;
  asm("v_cvt_pk_bf16_f32 %0, %1, %2" : "=v"(r) : "v"(lo), "v"(hi));
  return r;
}

DEV void glds16(const u16* g, u16* l) {
  __builtin_amdgcn_global_load_lds(
      (const __attribute__((address_space(1))) void*)g,
      (__attribute__((address_space(3))) void*)l, 16, 0, 0);
}

// ---- fused prep: [0,2048) xcvt | [2048,6144) transpose_w | [6144,6656) maskpack
__global__ __launch_bounds__(256) void prep(
    const float* __restrict__ k, const float* __restrict__ v,
    const float* __restrict__ q,
    const float* __restrict__ w0, const float* __restrict__ w1,
    const float* __restrict__ w2, const float* __restrict__ w3,
    const int* __restrict__ mask,
    u16* __restrict__ Xb, u16* __restrict__ WT,
    unsigned long long* __restrict__ Mb) {
  __shared__ u16 tile[32][33];
  const int bid = (int)blockIdx.x;
  const int tid = threadIdx.x;
  if (bid < 2048) {
    const size_t i0 = (size_t)bid * 256 + tid;
    for (size_t t = i0; t < 6291456; t += 524288) {
      const size_t e = t * 4;
      const float* src = (e < 8388608) ? k + e
                       : (e < 16777216) ? v + (e - 8388608)
                       : q + (e - 16777216);
      const f32x4 x = *(const f32x4*)src;
      u16x4 o;
#pragma unroll
      for (int r = 0; r < 4; ++r) o[r] = f2bf(x[r]);
      *(u16x4*)&Xb[e] = o;
    }
  } else if (bid < 6144) {
    const int lb = bid - 2048;
    const int mat = lb >> 10;
    const int bx = lb & 1023;
    const float* in = (mat == 0) ? w0 : (mat == 1) ? w1 : (mat == 2) ? w2 : w3;
    u16* o = WT + (size_t)mat * 1048576;
    const int bk = (bx & 31) << 5;
    const int bn = (bx >> 5) << 5;
    const int tx = tid & 31, ty = tid >> 5;
#pragma unroll
    for (int i = 0; i < 32; i += 8)
      tile[ty + i][tx] = f2bf(in[(size_t)(bk + ty + i) * 1024 + bn + tx]);
    __syncthreads();
#pragma unroll
    for (int i = 0; i < 32; i += 8)
      o[(size_t)(bn + ty + i) * 1024 + bk + tx] = tile[tx][ty + i];
  } else {
    const int lb = bid - 6144;
    const int qt = lb & 63, b = lb >> 6;
    const int w = tid >> 6, l = tid & 63;
    const int ln = l & 15, lg = l >> 4;
    const int* Mp = mask + ((size_t)b << 20) + ((size_t)(qt << 4) << 10);
    unsigned long long m = 0ull;
#pragma unroll
    for (int t = 0; t < 16; ++t) {
      const int key = (w << 8) + (t << 4) + ln;
#pragma unroll
      for (int r = 0; r < 4; ++r) {
        const int row = (lg << 2) + r;
        if (Mp[((size_t)row << 10) + key] != 0) m |= 1ull << ((t << 2) + r);
      }
    }
    Mb[((((size_t)b << 6) + qt) << 8) + tid] = m;
  }
}

// ---- QKV GEMM: 128x128 tile, BK=64, swizzled glds staging, T1 XCD swizzle ----
__global__ __launch_bounds__(256) void gemm_qkv(
    const u16* __restrict__ Xb, const u16* __restrict__ WTall,
    const float* __restrict__ bK, const float* __restrict__ bV,
    const float* __restrict__ bQ,
    u16* __restrict__ Kup, u16* __restrict__ VupT, u16* __restrict__ Qup) {
  __shared__ u16 As[8192];   // [128][64]
  __shared__ u16 Bs[8192];
  const int mode = blockIdx.y;
  const u16* A = Xb + (size_t)mode * 8388608;
  const u16* Bw = WTall + (size_t)mode * 1048576;
  const float* bias = (mode == 0) ? bK : (mode == 1) ? bV : bQ;

  const int tid = threadIdx.x;
  const int w = tid >> 6, l = tid & 63;
  const int ln = l & 15, lg = l >> 4;
  const int wr = w >> 1, wc = w & 1;
  // XCD-contiguous remap (512 = 8*64, bijective): XCD x owns an 8-m-row band
  const int bid0 = (int)blockIdx.x;
  const int sw = ((bid0 & 7) << 6) | (bid0 >> 3);
  const int mb = (sw >> 3) << 7;
  const int nb = (sw & 7) << 7;

  f32x4 acc[4][4] = {};
  const int ar = (wr << 6) + ln;
  const int br = (wc << 6) + ln;
  const int x7 = ln & 7;

  for (int k0 = 0; k0 < 1024; k0 += 64) {
#pragma unroll
    for (int i = 0; i < 4; ++i) {
      const int off = (i << 11) + (tid << 3);
      const int row = off >> 6;
      const int sc = ((((off >> 3) & 7) ^ (row & 7)) << 3);
      glds16(A + (size_t)(mb + row) * 1024 + k0 + sc, As + off);
      glds16(Bw + (size_t)(nb + row) * 1024 + k0 + sc, Bs + off);
    }
    __syncthreads();
#pragma unroll
    for (int kk = 0; kk < 2; ++kk) {
      const int g = (kk << 2) + lg;
      const int rc = (g ^ x7) << 3;
      bf16x8 aa[4], bb[4];
#pragma unroll
      for (int mt = 0; mt < 4; ++mt) {
        aa[mt] = *(const bf16x8*)&As[(ar + (mt << 4)) * 64 + rc];
        bb[mt] = *(const bf16x8*)&Bs[(br + (mt << 4)) * 64 + rc];
      }
#pragma unroll
      for (int mt = 0; mt < 4; ++mt)
#pragma unroll
        for (int nt = 0; nt < 4; ++nt)
          acc[mt][nt] = __builtin_amdgcn_mfma_f32_16x16x32_bf16(aa[mt], bb[nt], acc[mt][nt], 0, 0, 0);
    }
    __syncthreads();
  }

  const float scale = (mode == 2) ? 0.125f : 1.0f;
#pragma unroll
  for (int mt = 0; mt < 4; ++mt) {
    const int m0 = mb + (wr << 6) + (mt << 4) + (lg << 2);
    const int bb_ = m0 >> 10, s0 = m0 & 1023;
#pragma unroll
    for (int nt = 0; nt < 4; ++nt) {
      const int n = nb + (wc << 6) + (nt << 4) + ln;
      const float bval = bias[n];
      const int h = n >> 6, dh = n & 63;
      const size_t bh = (size_t)(bb_ * 16 + h);
      if (mode == 1) {
        const int wv = dh >> 4, lnv = dh & 15;
        const int kk = s0 >> 5, lgv = (s0 >> 3) & 3, e0 = s0 & 7;
        u16x4 pk;
#pragma unroll
        for (int r = 0; r < 4; ++r) pk[r] = f2bf(acc[mt][nt][r] + bval);
        *(u16x4*)&VupT[(bh << 16) + (wv << 14) + (kk << 9) + (lgv << 7) +
                       (lnv << 3) + e0] = pk;
      } else if (mode == 0) {
        const int half = dh >> 5, lg2 = (dh >> 3) & 3, e = dh & 7;
        const int T = s0 >> 4;
        u16* base = Kup + (bh << 16) + (T << 10) + (half << 9) + (lg2 << 7) + e;
#pragma unroll
        for (int r = 0; r < 4; ++r)
          base[((s0 & 15) + r) << 3] = f2bf(acc[mt][nt][r] + bval);
      } else {
#pragma unroll
        for (int r = 0; r < 4; ++r)
          Qup[((bh << 10) + s0 + r) * 64 + dh] =
              f2bf((acc[mt][nt][r] + bval) * scale);
      }
    }
  }
}

// ---- out-proj (BK=64 swizzled, T1) + folded combine2 (blocks >= 512) ----
__global__ __launch_bounds__(256) void gemm_out(
    const u16* __restrict__ Ctx, const u16* __restrict__ WTall,
    const float* __restrict__ bO, const u16* __restrict__ Pp,
    float* __restrict__ Out) {
  __shared__ u16 As[8192];
  __shared__ u16 Bs[8192];
  const int bid = (int)blockIdx.x;
  const int tid = threadIdx.x;

  if (bid >= 512) {
    float* Am = Out + 8388608;
    const size_t i = ((size_t)(bid - 512) * 256 + tid) * 8;
    const u16x4* q0 = (const u16x4*)&Pp[i];
    const u16x4* q1 = (const u16x4*)&Pp[8388608 + i];
    const u16x4 a0 = q0[0], a1 = q0[1], b0 = q1[0], b1 = q1[1];
    f32x4 lo, hi;
#pragma unroll
    for (int r = 0; r < 4; ++r) {
      lo[r] = (bf2f(a0[r]) + bf2f(b0[r])) * 0.0625f;
      hi[r] = (bf2f(a1[r]) + bf2f(b1[r])) * 0.0625f;
    }
    *(f32x4*)&Am[i] = lo;
    *(f32x4*)&Am[i + 4] = hi;
    return;
  }

  const u16* Bw = WTall + 3145728;
  const int w = tid >> 6, l = tid & 63;
  const int ln = l & 15, lg = l >> 4;
  const int wr = w >> 1, wc = w & 1;
  const int sw = ((bid & 7) << 6) | (bid >> 3);
  const int mb = (sw >> 3) << 7;
  const int nb = (sw & 7) << 7;

  f32x4 acc[4][4] = {};
  const int ar = (wr << 6) + ln;
  const int br = (wc << 6) + ln;
  const int x7 = ln & 7;

  for (int k0 = 0; k0 < 1024; k0 += 64) {
#pragma unroll
    for (int i = 0; i < 4; ++i) {
      const int off = (i << 11) + (tid << 3);
      const int row = off >> 6;
      const int sc = ((((off >> 3) & 7) ^ (row & 7)) << 3);
      glds16(Ctx + (size_t)(mb + row) * 1024 + k0 + sc, As + off);
      glds16(Bw + (size_t)(nb + row) * 1024 + k0 + sc, Bs + off);
    }
    __syncthreads();
#pragma unroll
    for (int kk = 0; kk < 2; ++kk) {
      const int g = (kk << 2) + lg;
      const int rc = (g ^ x7) << 3;
      bf16x8 aa[4], bb[4];
#pragma unroll
      for (int mt = 0; mt < 4; ++mt) {
        aa[mt] = *(const bf16x8*)&As[(ar + (mt << 4)) * 64 + rc];
        bb[mt] = *(const bf16x8*)&Bs[(br + (mt << 4)) * 64 + rc];
      }
#pragma unroll
      for (int mt = 0; mt < 4; ++mt)
#pragma unroll
        for (int nt = 0; nt < 4; ++nt)
          acc[mt][nt] = __builtin_amdgcn_mfma_f32_16x16x32_bf16(aa[mt], bb[nt], acc[mt][nt], 0, 0, 0);
    }
    __syncthreads();
  }
#pragma unroll
  for (int mt = 0; mt < 4; ++mt) {
    const int m0 = mb + (wr << 6) + (mt << 4) + (lg << 2);
#pragma unroll
    for (int nt = 0; nt < 4; ++nt) {
      const int n = nb + (wc << 6) + (nt << 4) + ln;
      const float bval = bO[n];
#pragma unroll
      for (int r = 0; r < 4; ++r)
        Out[(size_t)(m0 + r) * 1024 + n] = acc[mt][nt][r] + bval;
    }
  }
}

// ---- attention: 1024 blocks, 8 heads/block (round-16 proven body) ----
__global__ __launch_bounds__(256, 2) void attn_kernel(
    const u16* __restrict__ Qup, const u16* __restrict__ Kf,
    const u16* __restrict__ Vf, const unsigned long long* __restrict__ Mb,
    u16* __restrict__ Ctx, u16* __restrict__ Pp) {
  __shared__ u16 P_lds[16 * 1024];   // unnormalized exp(s-4), XOR-swizzled rows
  __shared__ float red_s[4][16];
  __shared__ float invs[16];

  const int tid = threadIdx.x;
  const int w = tid >> 6, l = tid & 63;
  const int ln = l & 15, lg = l >> 4;
  const int kg8 = lg << 3;

  const int bid = (int)blockIdx.x;
  const int b = bid & 7;
  const int idx = bid >> 3;
  const int qt = idx & 63;
  const int hs = idx >> 6;
  const int qb = qt << 4;

  const unsigned long long mbits = Mb[((((size_t)b << 6) + qt) << 8) + tid];

  u32x4 accp[8];

#pragma unroll 1
  for (int hh = 0; hh < 8; ++hh) {
    const int h = (hs << 3) + hh;
    const size_t bh = (size_t)(b * 16 + h);
    const u16* Qp = Qup + ((bh << 10) + qb) * 64;
    const u16* Kb = Kf + (bh << 16);
    const u16* Vb = Vf + (bh << 16) + ((size_t)w << 14);

    const bf16x8 qa0 = *(const bf16x8*)&Qp[ln * 64 + kg8];
    const bf16x8 qa1 = *(const bf16x8*)&Qp[ln * 64 + 32 + kg8];

    bf16x8 ka[3], kb[3];
#pragma unroll
    for (int p = 0; p < 3; ++p) {
      const int To = ((w << 4) + p) << 10;
      ka[p] = *(const bf16x8*)&Kb[To + (l << 3)];
      kb[p] = *(const bf16x8*)&Kb[To + 512 + (l << 3)];
    }

    float rsum[4] = {0, 0, 0, 0};
#pragma unroll
    for (int t = 0; t < 16; ++t) {
      const int s = t % 3;
      const bf16x8 k0 = ka[s], k1 = kb[s];
      if (t + 3 < 16) {
        const int To = ((w << 4) + t + 3) << 10;
        ka[s] = *(const bf16x8*)&Kb[To + (l << 3)];
        kb[s] = *(const bf16x8*)&Kb[To + 512 + (l << 3)];
      }
      f32x4 c = {0, 0, 0, 0};
      c = __builtin_amdgcn_mfma_f32_16x16x32_bf16(qa0, k0, c, 0, 0, 0);
      c = __builtin_amdgcn_mfma_f32_16x16x32_bf16(qa1, k1, c, 0, 0, 0);
      const int key = (w << 8) + (t << 4) + ln;
      float p[4];
#pragma unroll
      for (int r = 0; r < 4; ++r) {
        p[r] = ((mbits >> ((t << 2) + r)) & 1ull) ? 0.0f : __expf(c[r] - 4.0f);
        rsum[r] += p[r];
      }
      const u32 pk01 = cvtpk(p[0], p[1]);
      const u32 pk23 = cvtpk(p[2], p[3]);
      const int r0 = lg << 2;
      *(u16*)((char*)P_lds + ((((r0 + 0) << 11) + (key << 1)) ^ (((r0 + 0) & 7) << 4))) = (u16)pk01;
      *(u16*)((char*)P_lds + ((((r0 + 1) << 11) + (key << 1)) ^ (((r0 + 1) & 7) << 4))) = (u16)(pk01 >> 16);
      *(u16*)((char*)P_lds + ((((r0 + 2) << 11) + (key << 1)) ^ (((r0 + 2) & 7) << 4))) = (u16)pk23;
      *(u16*)((char*)P_lds + ((((r0 + 3) << 11) + (key << 1)) ^ (((r0 + 3) & 7) << 4))) = (u16)(pk23 >> 16);
    }

    // V prologue issued EARLY: loads fly under the shuffle-reduce VALU work
    bf16x8 vr[4];
#pragma unroll
    for (int p = 0; p < 4; ++p)
      vr[p] = *(const bf16x8*)&Vb[(p << 9) + (l << 3)];

#pragma unroll
    for (int off = 1; off < 16; off <<= 1) {
#pragma unroll
      for (int r = 0; r < 4; ++r) rsum[r] += __shfl_xor(rsum[r], off);
    }
    if (ln == 0) {
#pragma unroll
      for (int r = 0; r < 4; ++r) red_s[w][(lg << 2) + r] = rsum[r];
    }

    __syncthreads();
    float inv[4];
#pragma unroll
    for (int r = 0; r < 4; ++r) {
      const int row = (lg << 2) + r;
      inv[r] = 1.0f / (red_s[0][row] + red_s[1][row] + red_s[2][row] + red_s[3][row]);
    }
    if (ln == 0) {
#pragma unroll
      for (int r = 0; r < 4; ++r) invs[(lg << 2) + r] = inv[r];
    }

    f32x4 c0 = {0, 0, 0, 0}, c1 = {0, 0, 0, 0};
#pragma unroll
    for (int kk = 0; kk < 32; ++kk) {
      const int s = kk & 3;
      const bf16x8 vb = vr[s];
      if (kk + 4 < 32)
        vr[s] = *(const bf16x8*)&Vb[((kk + 4) << 9) + (l << 3)];
      const int a0 = ((ln << 11) + (((kk << 5) + kg8) << 1)) ^ ((ln & 7) << 4);
      const bf16x8 pa = *(const bf16x8*)((const char*)P_lds + a0);
      if (kk & 1)
        c1 = __builtin_amdgcn_mfma_f32_16x16x32_bf16(pa, vb, c1, 0, 0, 0);
      else
        c0 = __builtin_amdgcn_mfma_f32_16x16x32_bf16(pa, vb, c0, 0, 0, 0);
    }
    {
      const u32 q01 = cvtpk((c0[0] + c1[0]) * inv[0], (c0[1] + c1[1]) * inv[1]);
      const u32 q23 = cvtpk((c0[2] + c1[2]) * inv[2], (c0[3] + c1[3]) * inv[3]);
      u16* Cp = &Ctx[(((size_t)b << 10) + qb + (lg << 2)) * 1024 + (h << 6) + (w << 4) + ln];
      Cp[0] = (u16)q01;
      Cp[1024] = (u16)(q01 >> 16);
      Cp[2048] = (u16)q23;
      Cp[3072] = (u16)(q23 >> 16);
    }

    {
      const int row = tid >> 4;
      const float iv = invs[row];
#pragma unroll
      for (int i = 0; i < 8; ++i) {
        const int chunk = (tid & 15) + (i << 4);
        const int bo_ = ((row << 11) + (chunk << 4)) ^ ((row & 7) << 4);
        const u32x4 pu = *(const u32x4*)((const char*)P_lds + bo_);
        u32x4 o;
#pragma unroll
        for (int j = 0; j < 4; ++j) {
          const float plo = __builtin_bit_cast(float, pu[j] << 16) * iv;
          const float phi = __builtin_bit_cast(float, pu[j] & 0xFFFF0000u) * iv;
          if (hh == 0) {
            o[j] = cvtpk(plo, phi);
          } else {
            const u32 a = accp[i][j];
            const float alo = __builtin_bit_cast(float, a << 16);
            const float ahi = __builtin_bit_cast(float, a & 0xFFFF0000u);
            o[j] = cvtpk(alo + plo, ahi + phi);
          }
        }
        accp[i] = o;
      }
    }
    __syncthreads();
  }

  {
    const int row = tid >> 4;
    u16* Pg = Pp + ((size_t)hs << 23) + (((size_t)b << 10) + qb + row) * 1024;
#pragma unroll
    for (int i = 0; i < 8; ++i) {
      const int chunk = (tid & 15) + (i << 4);
      *(u32x4*)&Pg[chunk << 3] = accp[i];
    }
  }
}

extern "C" void kernel_launch(void* const* d_in, const int* in_sizes, int n_in,
                              void* d_out, int out_size, void* d_ws, size_t ws_size,
                              hipStream_t stream) {
  const float* k_in = (const float*)d_in[0];
  const float* v_in = (const float*)d_in[1];
  const float* q_in = (const float*)d_in[2];
  const int* mask = (const int*)d_in[3];
  const float* Wk = (const float*)d_in[4];
  const float* bk = (const float*)d_in[5];
  const float* Wv = (const float*)d_in[6];
  const float* bv = (const float*)d_in[7];
  const float* Wq = (const float*)d_in[8];
  const float* bq = (const float*)d_in[9];
  const float* Wo = (const float*)d_in[10];
  const float* bo = (const float*)d_in[11];

  float* out = (float*)d_out;                       // [8,1024,1024] f32 + amean

  // ws layout (u16 units): WT 4M | Xb [4M,29.36M) | Mb @29360128 (1MB) |
  //  Pp 2x8M @37748736 | Kf | Vf | Qup | Ctx  -> 209.7 MB total (proven)
  u16* ws = (u16*)d_ws;
  u16* WT = ws;
  u16* Xb = ws + 4194304;
  unsigned long long* Mb = (unsigned long long*)(ws + 29360128);
  u16* Pp = ws + 37748736;
  u16* Kf   = ws + 71303168;
  u16* Vf   = ws + 79691776;
  u16* Qup  = ws + 88080384;
  u16* Ctx  = ws + 96468992;

  prep<<<6656, 256, 0, stream>>>(k_in, v_in, q_in, Wk, Wv, Wq, Wo, mask,
                                 Xb, WT, Mb);
  gemm_qkv<<<dim3(512, 3), dim3(256), 0, stream>>>(
      Xb, WT, bk, bv, bq, Kf, Vf, Qup);
  attn_kernel<<<dim3(1024), dim3(256), 0, stream>>>(
      Qup, Kf, Vf, Mb, Ctx, Pp);
  gemm_out<<<4608, 256, 0, stream>>>(Ctx, WT, bo, Pp, out);
}